// Round 1
// baseline (135.966 us; speedup 1.0000x reference)
//
#include <hip/hip_runtime.h>
#include <math.h>

#define NPTS 8192
#define TPB 256
#define ICHUNKS (NPTS / TPB)     // 32 chunks of i, one i per thread
#define JCHUNKS 32
#define JTILE (NPTS / JCHUNKS)   // 256 j per block

// Main O(N^2) kernel: each block handles a 256(i) x 256(j) tile and
// accumulates partial sums of exp(-d2/ks) for (x,x), (z,z), (x,z).
__global__ __launch_bounds__(TPB) void itl_pairwise_kernel(
    const float* __restrict__ x, const float* __restrict__ z,
    const float* __restrict__ ks_p, float* __restrict__ sums)
{
    __shared__ float4 xs[JTILE];   // x_j coords + |x_j|^2
    __shared__ float4 zs[JTILE];   // z_j coords + |z_j|^2
    __shared__ float red[3][TPB / 64];

    const int t = threadIdx.x;
    const int ib = (blockIdx.x & (ICHUNKS - 1)) * TPB;
    const int jb = (blockIdx.x / ICHUNKS) * JTILE;

    const float negInv = -1.0f / ks_p[0];   // exp(-d2/ks) = exp(d2 * negInv)

    // Stage the j-tile into LDS (coords + norm).
    {
        const int j = jb + t;
        float a0 = x[3 * j], a1 = x[3 * j + 1], a2 = x[3 * j + 2];
        xs[t] = make_float4(a0, a1, a2, a0 * a0 + a1 * a1 + a2 * a2);
        float b0 = z[3 * j], b1 = z[3 * j + 1], b2 = z[3 * j + 2];
        zs[t] = make_float4(b0, b1, b2, b0 * b0 + b1 * b1 + b2 * b2);
    }

    // Own i-point in registers.
    const int i = ib + t;
    const float xi0 = x[3 * i], xi1 = x[3 * i + 1], xi2 = x[3 * i + 2];
    const float x2i = xi0 * xi0 + xi1 * xi1 + xi2 * xi2;
    const float zi0 = z[3 * i], zi1 = z[3 * i + 1], zi2 = z[3 * i + 2];
    const float z2i = zi0 * zi0 + zi1 * zi1 + zi2 * zi2;

    __syncthreads();

    float sxx = 0.f, szz = 0.f, sxz = 0.f;
#pragma unroll 8
    for (int jj = 0; jj < JTILE; ++jj) {
        const float4 a = xs[jj];   // broadcast (same addr all lanes)
        const float4 b = zs[jj];
        const float dxx = x2i + a.w - 2.f * (xi0 * a.x + xi1 * a.y + xi2 * a.z);
        const float dzz = z2i + b.w - 2.f * (zi0 * b.x + zi1 * b.y + zi2 * b.z);
        const float dxz = x2i + b.w - 2.f * (xi0 * b.x + xi1 * b.y + xi2 * b.z);
        sxx += __expf(dxx * negInv);
        szz += __expf(dzz * negInv);
        sxz += __expf(dxz * negInv);
    }

    // Wave (64-lane) shuffle reduction.
    for (int off = 32; off; off >>= 1) {
        sxx += __shfl_down(sxx, off);
        szz += __shfl_down(szz, off);
        sxz += __shfl_down(sxz, off);
    }
    const int lane = t & 63, wv = t >> 6;
    if (lane == 0) { red[0][wv] = sxx; red[1][wv] = szz; red[2][wv] = sxz; }
    __syncthreads();
    if (t == 0) {
        float a = red[0][0] + red[0][1] + red[0][2] + red[0][3];
        float b = red[1][0] + red[1][1] + red[1][2] + red[1][3];
        float c = red[2][0] + red[2][1] + red[2][2] + red[2][3];
        atomicAdd(&sums[0], a);
        atomicAdd(&sums[1], b);
        atomicAdd(&sums[2], c);
    }
}

// Finalize: means -> r * theta (double precision for the tiny tail math).
__global__ void itl_finalize_kernel(const float* __restrict__ sums,
                                    const float* __restrict__ ks_p,
                                    const float* __restrict__ theta_p,
                                    float* __restrict__ out_scalar)
{
    const double inv = 1.0 / ((double)NPTS * (double)NPTS);
    const double scale = 1.0 / sqrt(2.0 * M_PI * (double)ks_p[0]);
    const double mxx = (double)sums[0] * inv * scale;
    const double mzz = (double)sums[1] * inv * scale;
    const double mxz = (double)sums[2] * inv * scale;
    const double r = log(sqrt(mxx * mzz + 1e-5) / (mxz + 1e-5));
    out_scalar[0] = (float)(r * (double)theta_p[0]);
}

// Passthrough: out[0:24576] = x, out[24576:49152] = z (float4 vectorized).
__global__ void itl_copy_kernel(const float4* __restrict__ x,
                                const float4* __restrict__ z,
                                float4* __restrict__ out)
{
    const int t = blockIdx.x * blockDim.x + threadIdx.x;  // 0..12287
    if (t < 6144) out[t] = x[t];
    else          out[t] = z[t - 6144];
}

extern "C" void kernel_launch(void* const* d_in, const int* in_sizes, int n_in,
                              void* d_out, int out_size, void* d_ws, size_t ws_size,
                              hipStream_t stream) {
    const float* x     = (const float*)d_in[0];
    const float* z     = (const float*)d_in[1];
    const float* ks    = (const float*)d_in[2];
    const float* theta = (const float*)d_in[3];
    float* out  = (float*)d_out;
    float* sums = (float*)d_ws;

    hipMemsetAsync(d_ws, 0, 3 * sizeof(float), stream);

    // x||z passthrough: 49152 floats = 12288 float4.
    itl_copy_kernel<<<12288 / 256, 256, 0, stream>>>(
        (const float4*)x, (const float4*)z, (float4*)out);

    itl_pairwise_kernel<<<ICHUNKS * JCHUNKS, TPB, 0, stream>>>(x, z, ks, sums);

    itl_finalize_kernel<<<1, 1, 0, stream>>>(sums, ks, theta, out + NPTS * 3 * 2);
}

// Round 2
// 124.868 us; speedup vs baseline: 1.0889x; 1.0889x over previous
//
#include <hip/hip_runtime.h>
#include <math.h>

#define NPTS 8192
#define TPB 256
#define IPT 2
#define ISPAN (TPB * IPT)      // 512 i-points per block
#define ICH (NPTS / ISPAN)     // 16
#define JTILE 128
#define JCH (NPTS / JTILE)     // 64
#define NBLK (ICH * JCH)       // 1024 blocks

// Factored Gaussian: exp(-(x2i + x2j - 2 dot)/ks)
//   = exp2(-x2i*c2) * exp2(-x2j*c2) * exp2(dot * c1),  c2 = log2e/ks, c1 = 2*c2.
// j-tile staged with coords pre-scaled by c1 and exp2(-x2j*c2) in .w, so the
// inner loop is 3 fma (dot) + 1 v_exp + 1 fma (acc) per pair. The per-i factor
// exp2(-x2i*c2) multiplies the partial AFTER the j-loop.
__global__ __launch_bounds__(TPB) void itl_pairwise_kernel(
    const float* __restrict__ x, const float* __restrict__ z,
    const float* __restrict__ ks_p, float* __restrict__ partials,
    float* __restrict__ out)
{
    __shared__ float4 xs[JTILE];   // prescaled x_j coords + exp2(-|x_j|^2 c2)
    __shared__ float4 zs[JTILE];
    __shared__ float red[3][TPB / 64];

    const int t = threadIdx.x;
    const int ib = (blockIdx.x & (ICH - 1)) * ISPAN;
    const int jb = (blockIdx.x / ICH) * JTILE;

    const float c2 = 1.44269504088896340736f / ks_p[0];  // log2(e)/ks
    const float c1 = 2.0f * c2;

    // Folded passthrough: out[0:49152] = x || z, 12 float4 per block.
    if (t < 12) {
        const int k = blockIdx.x * 12 + t;
        const float4* src = (k < 6144) ? ((const float4*)x + k)
                                       : ((const float4*)z + (k - 6144));
        ((float4*)out)[k] = *src;
    }

    // Stage the j-tile (threads 0-127 do x, 128-255 do z).
    if (t < JTILE) {
        const int j = jb + t;
        const float a0 = x[3 * j], a1 = x[3 * j + 1], a2 = x[3 * j + 2];
        xs[t] = make_float4(a0 * c1, a1 * c1, a2 * c1,
                            exp2f(-(a0 * a0 + a1 * a1 + a2 * a2) * c2));
    } else {
        const int j = jb + (t - JTILE);
        const float b0 = z[3 * j], b1 = z[3 * j + 1], b2 = z[3 * j + 2];
        zs[t - JTILE] = make_float4(b0 * c1, b1 * c1, b2 * c1,
                                    exp2f(-(b0 * b0 + b1 * b1 + b2 * b2) * c2));
    }

    // Two i-points per thread (stride TPB keeps loads coalesced).
    const int i0 = ib + t, i1 = ib + t + TPB;
    const float x00 = x[3 * i0], x01 = x[3 * i0 + 1], x02 = x[3 * i0 + 2];
    const float x10 = x[3 * i1], x11 = x[3 * i1 + 1], x12 = x[3 * i1 + 2];
    const float z00 = z[3 * i0], z01 = z[3 * i0 + 1], z02 = z[3 * i0 + 2];
    const float z10 = z[3 * i1], z11 = z[3 * i1 + 1], z12 = z[3 * i1 + 2];
    const float ex0 = exp2f(-(x00 * x00 + x01 * x01 + x02 * x02) * c2);
    const float ex1 = exp2f(-(x10 * x10 + x11 * x11 + x12 * x12) * c2);
    const float ez0 = exp2f(-(z00 * z00 + z01 * z01 + z02 * z02) * c2);
    const float ez1 = exp2f(-(z10 * z10 + z11 * z11 + z12 * z12) * c2);

    __syncthreads();

    float sxx0 = 0.f, sxx1 = 0.f, szz0 = 0.f, szz1 = 0.f, sxz0 = 0.f, sxz1 = 0.f;
#pragma unroll 8
    for (int jj = 0; jj < JTILE; ++jj) {
        const float4 a = xs[jj];   // broadcast, conflict-free
        const float4 b = zs[jj];
        sxx0 += a.w * exp2f(x00 * a.x + x01 * a.y + x02 * a.z);
        sxx1 += a.w * exp2f(x10 * a.x + x11 * a.y + x12 * a.z);
        szz0 += b.w * exp2f(z00 * b.x + z01 * b.y + z02 * b.z);
        szz1 += b.w * exp2f(z10 * b.x + z11 * b.y + z12 * b.z);
        sxz0 += b.w * exp2f(x00 * b.x + x01 * b.y + x02 * b.z);
        sxz1 += b.w * exp2f(x10 * b.x + x11 * b.y + x12 * b.z);
    }

    float sxx = sxx0 * ex0 + sxx1 * ex1;
    float szz = szz0 * ez0 + szz1 * ez1;
    float sxz = sxz0 * ex0 + sxz1 * ex1;

    for (int off = 32; off; off >>= 1) {
        sxx += __shfl_down(sxx, off);
        szz += __shfl_down(szz, off);
        sxz += __shfl_down(sxz, off);
    }
    const int lane = t & 63, wv = t >> 6;
    if (lane == 0) { red[0][wv] = sxx; red[1][wv] = szz; red[2][wv] = sxz; }
    __syncthreads();
    if (t == 0) {
        partials[blockIdx.x]            = red[0][0] + red[0][1] + red[0][2] + red[0][3];
        partials[NBLK + blockIdx.x]     = red[1][0] + red[1][1] + red[1][2] + red[1][3];
        partials[2 * NBLK + blockIdx.x] = red[2][0] + red[2][1] + red[2][2] + red[2][3];
    }
}

// Reduce the 3x1024 per-block partials and compute r*theta (double tail math).
__global__ __launch_bounds__(TPB) void itl_finalize_kernel(
    const float* __restrict__ partials, const float* __restrict__ ks_p,
    const float* __restrict__ theta_p, float* __restrict__ out_scalar)
{
    __shared__ float red[3][TPB / 64];
    const int t = threadIdx.x;
    float s[3];
#pragma unroll
    for (int k = 0; k < 3; ++k) {
        float v = 0.f;
        for (int b = t; b < NBLK; b += TPB) v += partials[k * NBLK + b];
        for (int off = 32; off; off >>= 1) v += __shfl_down(v, off);
        s[k] = v;
    }
    if ((t & 63) == 0) {
        red[0][t >> 6] = s[0]; red[1][t >> 6] = s[1]; red[2][t >> 6] = s[2];
    }
    __syncthreads();
    if (t == 0) {
        const double inv = 1.0 / ((double)NPTS * (double)NPTS);
        const double scale = 1.0 / sqrt(2.0 * M_PI * (double)ks_p[0]);
        const double mxx = (double)(red[0][0] + red[0][1] + red[0][2] + red[0][3]) * inv * scale;
        const double mzz = (double)(red[1][0] + red[1][1] + red[1][2] + red[1][3]) * inv * scale;
        const double mxz = (double)(red[2][0] + red[2][1] + red[2][2] + red[2][3]) * inv * scale;
        const double r = log(sqrt(mxx * mzz + 1e-5) / (mxz + 1e-5));
        out_scalar[0] = (float)(r * (double)theta_p[0]);
    }
}

extern "C" void kernel_launch(void* const* d_in, const int* in_sizes, int n_in,
                              void* d_out, int out_size, void* d_ws, size_t ws_size,
                              hipStream_t stream) {
    const float* x     = (const float*)d_in[0];
    const float* z     = (const float*)d_in[1];
    const float* ks    = (const float*)d_in[2];
    const float* theta = (const float*)d_in[3];
    float* out      = (float*)d_out;
    float* partials = (float*)d_ws;   // 3 * NBLK floats

    itl_pairwise_kernel<<<NBLK, TPB, 0, stream>>>(x, z, ks, partials, out);
    itl_finalize_kernel<<<1, TPB, 0, stream>>>(partials, ks, theta, out + NPTS * 3 * 2);
}

// Round 3
// 101.482 us; speedup vs baseline: 1.3398x; 1.2304x over previous
//
#include <hip/hip_runtime.h>
#include <math.h>

#define NPTS 8192
#define TPB 256
#define IPT 2
#define ISPAN (TPB * IPT)      // 512 i-points per block
#define ICH (NPTS / ISPAN)     // 16
#define JTILE 128
#define JCH (NPTS / JTILE)     // 64
#define NBLK (ICH * JCH)       // 1024 blocks

// Raw v_exp_f32 (2^x). libm exp2f without fast-math lowers to the OCML
// precise path (~10 VALU ops: range check + ldexp fixup) — measured 4x
// slowdown of the inner loop in R2. Args here are bounded (|arg| < ~90),
// so the native instruction is safe and ~4 ULP accurate.
static __device__ __forceinline__ float fexp2(float v) {
    return __builtin_amdgcn_exp2f(v);
}

// Factored Gaussian: exp(-(x2i + x2j - 2 dot)/ks)
//   = exp2(-x2i*c2) * exp2(-x2j*c2) * exp2(dot * c1),  c2 = log2e/ks, c1 = 2*c2.
// j-tile staged with coords pre-scaled by c1 and exp2(-x2j*c2) in .w, so the
// inner loop is 3 fma (dot) + 1 v_exp + 1 fma (acc) per pair. The per-i factor
// exp2(-x2i*c2) multiplies the partial AFTER the j-loop.
__global__ __launch_bounds__(TPB) void itl_pairwise_kernel(
    const float* __restrict__ x, const float* __restrict__ z,
    const float* __restrict__ ks_p, float* __restrict__ partials,
    float* __restrict__ out)
{
    __shared__ float4 xs[JTILE];   // prescaled x_j coords + exp2(-|x_j|^2 c2)
    __shared__ float4 zs[JTILE];
    __shared__ float red[3][TPB / 64];

    const int t = threadIdx.x;
    const int ib = (blockIdx.x & (ICH - 1)) * ISPAN;
    const int jb = (blockIdx.x / ICH) * JTILE;

    const float c2 = 1.44269504088896340736f / ks_p[0];  // log2(e)/ks
    const float c1 = 2.0f * c2;

    // Folded passthrough: out[0:49152] = x || z, 12 float4 per block.
    if (t < 12) {
        const int k = blockIdx.x * 12 + t;
        const float4* src = (k < 6144) ? ((const float4*)x + k)
                                       : ((const float4*)z + (k - 6144));
        ((float4*)out)[k] = *src;
    }

    // Stage the j-tile (threads 0-127 do x, 128-255 do z).
    if (t < JTILE) {
        const int j = jb + t;
        const float a0 = x[3 * j], a1 = x[3 * j + 1], a2 = x[3 * j + 2];
        xs[t] = make_float4(a0 * c1, a1 * c1, a2 * c1,
                            fexp2(-(a0 * a0 + a1 * a1 + a2 * a2) * c2));
    } else {
        const int j = jb + (t - JTILE);
        const float b0 = z[3 * j], b1 = z[3 * j + 1], b2 = z[3 * j + 2];
        zs[t - JTILE] = make_float4(b0 * c1, b1 * c1, b2 * c1,
                                    fexp2(-(b0 * b0 + b1 * b1 + b2 * b2) * c2));
    }

    // Two i-points per thread (stride TPB keeps loads coalesced).
    const int i0 = ib + t, i1 = ib + t + TPB;
    const float x00 = x[3 * i0], x01 = x[3 * i0 + 1], x02 = x[3 * i0 + 2];
    const float x10 = x[3 * i1], x11 = x[3 * i1 + 1], x12 = x[3 * i1 + 2];
    const float z00 = z[3 * i0], z01 = z[3 * i0 + 1], z02 = z[3 * i0 + 2];
    const float z10 = z[3 * i1], z11 = z[3 * i1 + 1], z12 = z[3 * i1 + 2];
    const float ex0 = fexp2(-(x00 * x00 + x01 * x01 + x02 * x02) * c2);
    const float ex1 = fexp2(-(x10 * x10 + x11 * x11 + x12 * x12) * c2);
    const float ez0 = fexp2(-(z00 * z00 + z01 * z01 + z02 * z02) * c2);
    const float ez1 = fexp2(-(z10 * z10 + z11 * z11 + z12 * z12) * c2);

    __syncthreads();

    float sxx0 = 0.f, sxx1 = 0.f, szz0 = 0.f, szz1 = 0.f, sxz0 = 0.f, sxz1 = 0.f;
#pragma unroll 8
    for (int jj = 0; jj < JTILE; ++jj) {
        const float4 a = xs[jj];   // broadcast, conflict-free
        const float4 b = zs[jj];
        sxx0 += a.w * fexp2(x00 * a.x + x01 * a.y + x02 * a.z);
        sxx1 += a.w * fexp2(x10 * a.x + x11 * a.y + x12 * a.z);
        szz0 += b.w * fexp2(z00 * b.x + z01 * b.y + z02 * b.z);
        szz1 += b.w * fexp2(z10 * b.x + z11 * b.y + z12 * b.z);
        sxz0 += b.w * fexp2(x00 * b.x + x01 * b.y + x02 * b.z);
        sxz1 += b.w * fexp2(x10 * b.x + x11 * b.y + x12 * b.z);
    }

    float sxx = sxx0 * ex0 + sxx1 * ex1;
    float szz = szz0 * ez0 + szz1 * ez1;
    float sxz = sxz0 * ex0 + sxz1 * ex1;

    for (int off = 32; off; off >>= 1) {
        sxx += __shfl_down(sxx, off);
        szz += __shfl_down(szz, off);
        sxz += __shfl_down(sxz, off);
    }
    const int lane = t & 63, wv = t >> 6;
    if (lane == 0) { red[0][wv] = sxx; red[1][wv] = szz; red[2][wv] = sxz; }
    __syncthreads();
    if (t == 0) {
        partials[blockIdx.x]            = red[0][0] + red[0][1] + red[0][2] + red[0][3];
        partials[NBLK + blockIdx.x]     = red[1][0] + red[1][1] + red[1][2] + red[1][3];
        partials[2 * NBLK + blockIdx.x] = red[2][0] + red[2][1] + red[2][2] + red[2][3];
    }
}

// Reduce the 3x1024 per-block partials and compute r*theta (double tail math).
__global__ __launch_bounds__(TPB) void itl_finalize_kernel(
    const float* __restrict__ partials, const float* __restrict__ ks_p,
    const float* __restrict__ theta_p, float* __restrict__ out_scalar)
{
    __shared__ float red[3][TPB / 64];
    const int t = threadIdx.x;
    float s[3];
#pragma unroll
    for (int k = 0; k < 3; ++k) {
        float v = 0.f;
        for (int b = t; b < NBLK; b += TPB) v += partials[k * NBLK + b];
        for (int off = 32; off; off >>= 1) v += __shfl_down(v, off);
        s[k] = v;
    }
    if ((t & 63) == 0) {
        red[0][t >> 6] = s[0]; red[1][t >> 6] = s[1]; red[2][t >> 6] = s[2];
    }
    __syncthreads();
    if (t == 0) {
        const double inv = 1.0 / ((double)NPTS * (double)NPTS);
        const double scale = 1.0 / sqrt(2.0 * M_PI * (double)ks_p[0]);
        const double mxx = (double)(red[0][0] + red[0][1] + red[0][2] + red[0][3]) * inv * scale;
        const double mzz = (double)(red[1][0] + red[1][1] + red[1][2] + red[1][3]) * inv * scale;
        const double mxz = (double)(red[2][0] + red[2][1] + red[2][2] + red[2][3]) * inv * scale;
        const double r = log(sqrt(mxx * mzz + 1e-5) / (mxz + 1e-5));
        out_scalar[0] = (float)(r * (double)theta_p[0]);
    }
}

extern "C" void kernel_launch(void* const* d_in, const int* in_sizes, int n_in,
                              void* d_out, int out_size, void* d_ws, size_t ws_size,
                              hipStream_t stream) {
    const float* x     = (const float*)d_in[0];
    const float* z     = (const float*)d_in[1];
    const float* ks    = (const float*)d_in[2];
    const float* theta = (const float*)d_in[3];
    float* out      = (float*)d_out;
    float* partials = (float*)d_ws;   // 3 * NBLK floats

    itl_pairwise_kernel<<<NBLK, TPB, 0, stream>>>(x, z, ks, partials, out);
    itl_finalize_kernel<<<1, TPB, 0, stream>>>(partials, ks, theta, out + NPTS * 3 * 2);
}

// Round 4
// 97.722 us; speedup vs baseline: 1.3914x; 1.0385x over previous
//
#include <hip/hip_runtime.h>
#include <math.h>

#define NPTS 8192
#define TPB 256
#define IPT 4
#define ISPAN (TPB * IPT)       // 1024 i-points per block
#define NSTRIP (NPTS / ISPAN)   // 8 i-strips
#define JTILE 128
#define JT_TOTAL (NPTS / JTILE) // 64 j-tiles
#define BPS (ISPAN / JTILE)     // 8 band tiles per strip (diagonal straddle)
#define NXZ (NSTRIP * JT_TOTAL) // 512 blocks: full x-z matrix
#define NTRI 288                // sum_{s=0..7} (64 - 8s): upper-tri incl band
#define NBLK (NXZ + 2 * NTRI)   // 1088

// Raw v_exp_f32 (2^x). libm exp2f lowers to the OCML precise path (~10 VALU
// ops) — measured 4x inner-loop cost in R2. Args bounded here, native is safe.
// R3 counters: v_exp_f32 is ~16 cyc/wave64 (4 lanes/cyc) — exp dominates VALU.
static __device__ __forceinline__ float fexp2(float v) {
    return __builtin_amdgcn_exp2f(v);
}

// Factored Gaussian: exp(-(|pi|^2+|pj|^2-2 dot)/ks)
//   = E(i) * E(j) * exp2(dot*c1),  E(p)=exp2(-|p|^2 c2), c2=log2e/ks, c1=2c2.
// Symmetry: sum_full(xx) = 2*sum_{i<j} + N (ditto zz); xz is full.
// Block b decodes to (matrix, i-strip s, j-tile jt): xz covers all (s,jt);
// xx/zz cover jt >= 8s only; band tiles (jt in [8s,8s+8)) mask j>i.
__global__ __launch_bounds__(TPB) void itl_pairwise_kernel(
    const float* __restrict__ x, const float* __restrict__ z,
    const float* __restrict__ ks_p, float* __restrict__ partials,
    float* __restrict__ out)
{
    __shared__ float4 js[JTILE];   // prescaled j coords + E(j)
    __shared__ float red[TPB / 64];

    const int t = threadIdx.x;
    const int b = blockIdx.x;

    // Decode block -> (mat, s, jt, band). Scalar, once per block.
    int mat, s = 0, jt;
    bool band;
    if (b < NXZ) {
        mat = 0; s = b >> 6; jt = b & 63; band = false;
    } else {
        int r = b - NXZ;
        mat = (r < NTRI) ? 1 : 2;        // 1 = xx, 2 = zz
        if (mat == 2) r -= NTRI;
        while (r >= JT_TOTAL - BPS * s) { r -= JT_TOTAL - BPS * s; ++s; }
        jt = BPS * s + r;
        band = (r < BPS);
    }
    const int ib = s * ISPAN;
    const int jb = jt * JTILE;

    const float c2 = 1.44269504088896340736f / ks_p[0];  // log2(e)/ks
    const float c1 = 2.0f * c2;

    // Folded passthrough: out[0:49152] = x || z (12288 float4 over 1088 blocks).
    if (t < 12) {
        const int k = b * 12 + t;
        if (k < 12288) {
            const float4* src = (k < 6144) ? ((const float4*)x + k)
                                           : ((const float4*)z + (k - 6144));
            ((float4*)out)[k] = *src;
        }
    }

    const float* __restrict__ isrc = (mat == 2) ? z : x;
    const float* __restrict__ jsrc = (mat == 1) ? x : z;

    if (t < JTILE) {
        const int j = jb + t;
        const float a0 = jsrc[3 * j], a1 = jsrc[3 * j + 1], a2 = jsrc[3 * j + 2];
        js[t] = make_float4(a0 * c1, a1 * c1, a2 * c1,
                            fexp2(-(a0 * a0 + a1 * a1 + a2 * a2) * c2));
    }

    // 4 i-points per thread (stride TPB keeps loads coalesced).
    float p0[IPT], p1[IPT], p2[IPT], ef[IPT];
    int iv[IPT];
#pragma unroll
    for (int k = 0; k < IPT; ++k) {
        const int i = ib + t + k * TPB;
        iv[k] = i;
        p0[k] = isrc[3 * i]; p1[k] = isrc[3 * i + 1]; p2[k] = isrc[3 * i + 2];
        ef[k] = fexp2(-(p0[k] * p0[k] + p1[k] * p1[k] + p2[k] * p2[k]) * c2);
    }

    __syncthreads();

    float acc[IPT] = {0.f, 0.f, 0.f, 0.f};
    if (!band) {
        // 1 ds_read_b128 + 4x(3 fma + v_exp + fma) per iter; 4 indep exp chains.
#pragma unroll 8
        for (int jj = 0; jj < JTILE; ++jj) {
            const float4 a = js[jj];   // broadcast, conflict-free
#pragma unroll
            for (int k = 0; k < IPT; ++k)
                acc[k] += a.w * fexp2(p0[k] * a.x + p1[k] * a.y + p2[k] * a.z);
        }
    } else {
        // Diagonal-straddling tile: strict upper only (j > i).
#pragma unroll 4
        for (int jj = 0; jj < JTILE; ++jj) {
            const float4 a = js[jj];
            const int j = jb + jj;
#pragma unroll
            for (int k = 0; k < IPT; ++k) {
                const float v = a.w * fexp2(p0[k] * a.x + p1[k] * a.y + p2[k] * a.z);
                acc[k] += (j > iv[k]) ? v : 0.0f;
            }
        }
    }

    float ssum = acc[0] * ef[0] + acc[1] * ef[1] + acc[2] * ef[2] + acc[3] * ef[3];
    for (int off = 32; off; off >>= 1) ssum += __shfl_down(ssum, off);
    if ((t & 63) == 0) red[t >> 6] = ssum;
    __syncthreads();
    if (t == 0) partials[b] = red[0] + red[1] + red[2] + red[3];
}

// Segment-reduce partials; apply symmetry (2*upper + N) and tail math.
__global__ __launch_bounds__(TPB) void itl_finalize_kernel(
    const float* __restrict__ partials, const float* __restrict__ ks_p,
    const float* __restrict__ theta_p, float* __restrict__ out_scalar)
{
    __shared__ float red[3][TPB / 64];
    const int t = threadIdx.x;
    float v0 = 0.f, v1 = 0.f, v2 = 0.f;
    for (int i = t; i < NXZ; i += TPB) v0 += partials[i];
    for (int i = t; i < NTRI; i += TPB) v1 += partials[NXZ + i];
    for (int i = t; i < NTRI; i += TPB) v2 += partials[NXZ + NTRI + i];
    for (int off = 32; off; off >>= 1) {
        v0 += __shfl_down(v0, off);
        v1 += __shfl_down(v1, off);
        v2 += __shfl_down(v2, off);
    }
    if ((t & 63) == 0) {
        red[0][t >> 6] = v0; red[1][t >> 6] = v1; red[2][t >> 6] = v2;
    }
    __syncthreads();
    if (t == 0) {
        const double Sxz = (double)(red[0][0] + red[0][1] + red[0][2] + red[0][3]);
        const double Sxx = 2.0 * (double)(red[1][0] + red[1][1] + red[1][2] + red[1][3]) + (double)NPTS;
        const double Szz = 2.0 * (double)(red[2][0] + red[2][1] + red[2][2] + red[2][3]) + (double)NPTS;
        const double inv = 1.0 / ((double)NPTS * (double)NPTS);
        const double scale = 1.0 / sqrt(2.0 * M_PI * (double)ks_p[0]);
        const double mxx = Sxx * inv * scale;
        const double mzz = Szz * inv * scale;
        const double mxz = Sxz * inv * scale;
        const double r = log(sqrt(mxx * mzz + 1e-5) / (mxz + 1e-5));
        out_scalar[0] = (float)(r * (double)theta_p[0]);
    }
}

extern "C" void kernel_launch(void* const* d_in, const int* in_sizes, int n_in,
                              void* d_out, int out_size, void* d_ws, size_t ws_size,
                              hipStream_t stream) {
    const float* x     = (const float*)d_in[0];
    const float* z     = (const float*)d_in[1];
    const float* ks    = (const float*)d_in[2];
    const float* theta = (const float*)d_in[3];
    float* out      = (float*)d_out;
    float* partials = (float*)d_ws;   // NBLK floats

    itl_pairwise_kernel<<<NBLK, TPB, 0, stream>>>(x, z, ks, partials, out);
    itl_finalize_kernel<<<1, TPB, 0, stream>>>(partials, ks, theta, out + NPTS * 3 * 2);
}

// Round 5
// 93.812 us; speedup vs baseline: 1.4493x; 1.0417x over previous
//
#include <hip/hip_runtime.h>
#include <math.h>

#define NPTS 8192
#define TPB 256
#define IPT 4
#define ISPAN (TPB * IPT)       // 1024 i-points per block
#define NSTRIP (NPTS / ISPAN)   // 8 i-strips
#define JTILE 64
#define JT_TOTAL (NPTS / JTILE) // 128 j-tiles
#define BPS (ISPAN / JTILE)     // 16 band tiles per strip (diagonal straddle)
#define NXZ (NSTRIP * JT_TOTAL) // 1024 blocks: full x-z matrix
#define NTRI 576                // sum_{s=0..7} (128 - 16s): upper-tri incl band
#define NBLK (NXZ + 2 * NTRI)   // 2176  -> 8704 waves ~= full 8192-wave capacity

// Raw v_exp_f32 (2^x). libm exp2f lowers to the OCML precise path (~10 VALU
// ops) — measured 4x inner-loop cost in R2. Args bounded here, native is safe.
// R3/R4 counters: v_exp_f32 ~16 cyc/wave64 — exp is ~2/3 of VALU issue.
static __device__ __forceinline__ float fexp2(float v) {
    return __builtin_amdgcn_exp2f(v);
}

// Factored Gaussian: exp(-(|pi|^2+|pj|^2-2 dot)/ks)
//   = E(i) * E(j) * exp2(dot*c1),  E(p)=exp2(-|p|^2 c2), c2=log2e/ks, c1=2c2.
// Symmetry: sum_full(xx) = 2*sum_{i<j} + N (ditto zz); xz is full.
// R4->R5: JTILE 128->64 doubles block count to 2176 so waves/SIMD goes
// 4.25 -> 8.5 (R4 showed VALUBusy 55% = latency-starved at half occupancy).
__global__ __launch_bounds__(TPB) void itl_pairwise_kernel(
    const float* __restrict__ x, const float* __restrict__ z,
    const float* __restrict__ ks_p, float* __restrict__ partials,
    float* __restrict__ out)
{
    __shared__ float4 js[JTILE];   // prescaled j coords + E(j)
    __shared__ float red[TPB / 64];

    const int t = threadIdx.x;
    const int b = blockIdx.x;

    // Decode block -> (mat, s, jt, band). Scalar, once per block.
    int mat, s = 0, jt;
    bool band;
    if (b < NXZ) {
        mat = 0; s = b >> 7; jt = b & 127; band = false;
    } else {
        int r = b - NXZ;
        mat = (r < NTRI) ? 1 : 2;        // 1 = xx, 2 = zz
        if (mat == 2) r -= NTRI;
        while (r >= JT_TOTAL - BPS * s) { r -= JT_TOTAL - BPS * s; ++s; }
        jt = BPS * s + r;
        band = (r < BPS);
    }
    const int ib = s * ISPAN;
    const int jb = jt * JTILE;

    const float c2 = 1.44269504088896340736f / ks_p[0];  // log2(e)/ks
    const float c1 = 2.0f * c2;

    // Folded passthrough: out[0:49152] = x || z (12288 float4 over 2176 blocks).
    if (t < 6) {
        const int k = b * 6 + t;
        if (k < 12288) {
            const float4* src = (k < 6144) ? ((const float4*)x + k)
                                           : ((const float4*)z + (k - 6144));
            ((float4*)out)[k] = *src;
        }
    }

    const float* __restrict__ isrc = (mat == 2) ? z : x;
    const float* __restrict__ jsrc = (mat == 1) ? x : z;

    if (t < JTILE) {
        const int j = jb + t;
        const float a0 = jsrc[3 * j], a1 = jsrc[3 * j + 1], a2 = jsrc[3 * j + 2];
        js[t] = make_float4(a0 * c1, a1 * c1, a2 * c1,
                            fexp2(-(a0 * a0 + a1 * a1 + a2 * a2) * c2));
    }

    // 4 i-points per thread (stride TPB keeps loads coalesced).
    float p0[IPT], p1[IPT], p2[IPT], ef[IPT];
    int iv[IPT];
#pragma unroll
    for (int k = 0; k < IPT; ++k) {
        const int i = ib + t + k * TPB;
        iv[k] = i;
        p0[k] = isrc[3 * i]; p1[k] = isrc[3 * i + 1]; p2[k] = isrc[3 * i + 2];
        ef[k] = fexp2(-(p0[k] * p0[k] + p1[k] * p1[k] + p2[k] * p2[k]) * c2);
    }

    __syncthreads();

    float acc[IPT] = {0.f, 0.f, 0.f, 0.f};
    if (!band) {
        // 1 ds_read_b128 + 4x(3 fma + v_exp + fma) per iter; 4 indep exp chains.
#pragma unroll 8
        for (int jj = 0; jj < JTILE; ++jj) {
            const float4 a = js[jj];   // broadcast, conflict-free
#pragma unroll
            for (int k = 0; k < IPT; ++k)
                acc[k] += a.w * fexp2(p0[k] * a.x + p1[k] * a.y + p2[k] * a.z);
        }
    } else {
        // Diagonal-straddling tile: strict upper only (j > i).
#pragma unroll 4
        for (int jj = 0; jj < JTILE; ++jj) {
            const float4 a = js[jj];
            const int j = jb + jj;
#pragma unroll
            for (int k = 0; k < IPT; ++k) {
                const float v = a.w * fexp2(p0[k] * a.x + p1[k] * a.y + p2[k] * a.z);
                acc[k] += (j > iv[k]) ? v : 0.0f;
            }
        }
    }

    float ssum = acc[0] * ef[0] + acc[1] * ef[1] + acc[2] * ef[2] + acc[3] * ef[3];
    for (int off = 32; off; off >>= 1) ssum += __shfl_down(ssum, off);
    if ((t & 63) == 0) red[t >> 6] = ssum;
    __syncthreads();
    if (t == 0) partials[b] = red[0] + red[1] + red[2] + red[3];
}

// Segment-reduce partials; apply symmetry (2*upper + N) and tail math.
__global__ __launch_bounds__(TPB) void itl_finalize_kernel(
    const float* __restrict__ partials, const float* __restrict__ ks_p,
    const float* __restrict__ theta_p, float* __restrict__ out_scalar)
{
    __shared__ float red[3][TPB / 64];
    const int t = threadIdx.x;
    float v0 = 0.f, v1 = 0.f, v2 = 0.f;
    for (int i = t; i < NXZ; i += TPB) v0 += partials[i];
    for (int i = t; i < NTRI; i += TPB) v1 += partials[NXZ + i];
    for (int i = t; i < NTRI; i += TPB) v2 += partials[NXZ + NTRI + i];
    for (int off = 32; off; off >>= 1) {
        v0 += __shfl_down(v0, off);
        v1 += __shfl_down(v1, off);
        v2 += __shfl_down(v2, off);
    }
    if ((t & 63) == 0) {
        red[0][t >> 6] = v0; red[1][t >> 6] = v1; red[2][t >> 6] = v2;
    }
    __syncthreads();
    if (t == 0) {
        const double Sxz = (double)(red[0][0] + red[0][1] + red[0][2] + red[0][3]);
        const double Sxx = 2.0 * (double)(red[1][0] + red[1][1] + red[1][2] + red[1][3]) + (double)NPTS;
        const double Szz = 2.0 * (double)(red[2][0] + red[2][1] + red[2][2] + red[2][3]) + (double)NPTS;
        const double inv = 1.0 / ((double)NPTS * (double)NPTS);
        const double scale = 1.0 / sqrt(2.0 * M_PI * (double)ks_p[0]);
        const double mxx = Sxx * inv * scale;
        const double mzz = Szz * inv * scale;
        const double mxz = Sxz * inv * scale;
        const double r = log(sqrt(mxx * mzz + 1e-5) / (mxz + 1e-5));
        out_scalar[0] = (float)(r * (double)theta_p[0]);
    }
}

extern "C" void kernel_launch(void* const* d_in, const int* in_sizes, int n_in,
                              void* d_out, int out_size, void* d_ws, size_t ws_size,
                              hipStream_t stream) {
    const float* x     = (const float*)d_in[0];
    const float* z     = (const float*)d_in[1];
    const float* ks    = (const float*)d_in[2];
    const float* theta = (const float*)d_in[3];
    float* out      = (float*)d_out;
    float* partials = (float*)d_ws;   // NBLK floats

    itl_pairwise_kernel<<<NBLK, TPB, 0, stream>>>(x, z, ks, partials, out);
    itl_finalize_kernel<<<1, TPB, 0, stream>>>(partials, ks, theta, out + NPTS * 3 * 2);
}